// Round 7
// baseline (1311.657 us; speedup 1.0000x reference)
//
#include <hip/hip_runtime.h>
#include <stdint.h>

// LatentODE fused, 2 batch-tiles per wave (ILP): B=8192, T=100, D=44, NH=64, L=8.
// 256 blocks x 1 wave; each wave carries TWO independent 16-batch chains so
// each chain's DS/MFMA latency is filled by the other chain's instructions.
// Weights (A-frags) shared across tiles. LDS transpose per tile, batched
// write/write/read/read under one lgkmcnt. Biases ride spare K-rows.
// R7: conservative rewrite of R5 (pointer-decay lambda params, no
// reference-to-array types) after two container failures on the R5 source.

constexpr int B_ = 8192, T_ = 100, D_ = 44, NH_ = 64, L_ = 8;
constexpr int NT = 2;  // batch-tiles per wave

typedef __bf16 bf16x8 __attribute__((ext_vector_type(8)));
typedef float f32x4 __attribute__((ext_vector_type(4)));
typedef uint32_t u32x4 __attribute__((ext_vector_type(4)));
typedef uint32_t u32x2 __attribute__((ext_vector_type(2)));

__device__ __forceinline__ float fexp2(float x) { return __builtin_amdgcn_exp2f(x); }
__device__ __forceinline__ float frcp(float x) { return __builtin_amdgcn_rcpf(x); }
__device__ __forceinline__ float fexp(float x) { return fexp2(x * 1.44269504088896341f); }
__device__ __forceinline__ float tanh_f(float x) {
  float e = fexp2(x * 2.88539008177792681f);
  return 1.0f - 2.0f * frcp(e + 1.0f);
}
__device__ __forceinline__ float elu_f(float x) { return x > 0.0f ? x : (fexp(x) - 1.0f); }
__device__ __forceinline__ uint32_t f2bs(float x) {
  return (uint32_t)__builtin_bit_cast(unsigned short, (__bf16)x);
}
__device__ __forceinline__ uint32_t pk(float lo, float hi) { return f2bs(lo) | (f2bs(hi) << 16); }
__device__ __forceinline__ uint32_t sh(uint32_t v, int s) { return (uint32_t)__shfl((int)v, s, 64); }
__device__ __forceinline__ f32x4 mfma16(bf16x8 a, bf16x8 b, f32x4 c) {
  return __builtin_amdgcn_mfma_f32_16x16x32_bf16(a, b, c, 0, 0, 0);
}
__device__ __forceinline__ bf16x8 pack8(float a, float b, float c, float d,
                                        float e, float f, float g, float h) {
  u32x4 u = {pk(a, b), pk(c, d), pk(e, f), pk(g, h)};
  return __builtin_bit_cast(bf16x8, u);
}
__device__ __forceinline__ float f4get(const float4& f, int i) {
  return i == 0 ? f.x : (i == 1 ? f.y : (i == 2 ? f.z : f.w));
}

// z (C-layout f32 rows 0-7 on lanes q<2) -> B-frag; row 8 := 1.0 (bias row).
__device__ __forceinline__ bf16x8 build_bz(f32x4 z, int c, int q) {
  uint32_t p01 = pk(z[0], z[1]), p23 = pk(z[2], z[3]);
  u32x4 u = {sh(p01, c), sh(p23, c), sh(p01, c + 16), sh(p23, c + 16)};
  if (q == 1) u[0] = 0x3f80u;  // k=8 -> 1.0, k=9 -> 0
  return __builtin_bit_cast(bf16x8, u);
}

__global__ __launch_bounds__(64, 1) void fused_kernel(
    const float* __restrict__ x, const float* __restrict__ mask,
    const float* __restrict__ eps,
    const float* __restrict__ Wi2h, const float* __restrict__ bi2h,
    const float* __restrict__ Wh2o, const float* __restrict__ bh2o,
    const float* __restrict__ Wf1, const float* __restrict__ bf1,
    const float* __restrict__ Wf2, const float* __restrict__ bf2,
    const float* __restrict__ Wf3, const float* __restrict__ bf3,
    const float* __restrict__ Wd1, const float* __restrict__ bd1,
    const float* __restrict__ Wd2, const float* __restrict__ bd2,
    float* __restrict__ part) {
  const int lane = threadIdx.x;
  const int c = lane & 15, q = lane >> 4;
  const int r0 = blockIdx.x * (16 * NT);

  __shared__ uint32_t tbuf[NT][576];

  // Both-tile LDS transpose: C-layout [64 x 16] f32 -> 2 B-frags (K=64).
  // All writes (both tiles) then all reads: one fine-grained lgkmcnt window.
  // Pointer-decay params (f32x4 (*)[4]) -- no reference-to-array types.
  auto repack2 = [&](const f32x4 (*e)[4], bf16x8 (*bh)[2]) {
#pragma unroll
    for (int nt = 0; nt < NT; ++nt)
#pragma unroll
      for (int tau = 0; tau < 4; ++tau) {
        u32x2 w = {pk(e[nt][tau][0], e[nt][tau][1]), pk(e[nt][tau][2], e[nt][tau][3])};
        *(u32x2*)(&tbuf[nt][0] + 36 * c + 8 * tau + 2 * q) = w;
      }
#pragma unroll
    for (int nt = 0; nt < NT; ++nt)
#pragma unroll
      for (int ks = 0; ks < 2; ++ks) {
        u32x4 r = *(const u32x4*)(&tbuf[nt][0] + 36 * c + 16 * ks + 4 * q);
        bh[nt][ks] = __builtin_bit_cast(bf16x8, r);
      }
  };

  // ================= Phase 1: backward RNN scan =================
  // State rows: [h 0..63 ; obs 64..107 ; bias 108].
  bf16x8 Ai[4][4];
#pragma unroll
  for (int tau = 0; tau < 4; ++tau)
#pragma unroll
    for (int ks = 0; ks < 4; ++ks) {
      bf16x8 f;
      const int m = 16 * tau + c;
#pragma unroll
      for (int i = 0; i < 8; ++i) {
        const int k = 32 * ks + 8 * q + i;
        float v = 0.0f;
        if (k < 64) v = Wi2h[(44 + k) * 64 + m];
        else if (k < 108) v = Wi2h[(k - 64) * 64 + m];
        else if (k == 108) v = bi2h[m];
        f[i] = (__bf16)v;
      }
      Ai[tau][ks] = f;
    }
  bf16x8 Ah2o[2];
#pragma unroll
  for (int ks = 0; ks < 2; ++ks) {
    bf16x8 f;
#pragma unroll
    for (int i = 0; i < 8; ++i) f[i] = (__bf16)Wh2o[(32 * ks + 8 * q + i) * 16 + c];
    Ah2o[ks] = f;
  }
  f32x4 bo;
#pragma unroll
  for (int r = 0; r < 4; ++r) bo[r] = bh2o[4 * q + r];

  const float* xrow0 = x + (size_t)(r0 + c) * T_ * D_;
  const float* mrow0 = mask + (size_t)(r0 + c) * T_ * D_;
  const float* xrow1 = x + (size_t)(r0 + 16 + c) * T_ * D_;
  const float* mrow1 = mask + (size_t)(r0 + 16 + c) * T_ * D_;

  float4 rx[NT][4], rm[NT][4];
  bf16x8 po2[NT], po3[NT];

  auto issue_obs = [&](int t) {
#pragma unroll
    for (int nt = 0; nt < NT; ++nt) {
      const float4* xr = (const float4*)((nt ? xrow1 : xrow0) + (size_t)t * D_);
      const float4* mr = (const float4*)((nt ? mrow1 : mrow0) + (size_t)t * D_);
      rx[nt][0] = xr[2 * q];     rx[nt][1] = xr[2 * q + 1];
      rm[nt][0] = mr[2 * q];     rm[nt][1] = mr[2 * q + 1];
      float4 zz = {0.f, 0.f, 0.f, 0.f};
      rx[nt][2] = zz; rx[nt][3] = zz; rm[nt][2] = zz; rm[nt][3] = zz;
      if (q == 0) { rx[nt][2] = xr[8];  rx[nt][3] = xr[9];
                    rm[nt][2] = mr[8];  rm[nt][3] = mr[9]; }
      else if (q == 1) { rx[nt][2] = xr[10]; rm[nt][2] = mr[10]; }
    }
  };
  auto pack_obs = [&]() {
#pragma unroll
    for (int nt = 0; nt < NT; ++nt) {
      const float4 A0 = rx[nt][0], A1 = rx[nt][1], B0 = rx[nt][2], B1 = rx[nt][3];
      const float4 M0 = rm[nt][0], M1 = rm[nt][1], N0 = rm[nt][2], N1 = rm[nt][3];
      po2[nt] = pack8(A0.x * M0.x, A0.y * M0.y, A0.z * M0.z, A0.w * M0.w,
                      A1.x * M1.x, A1.y * M1.y, A1.z * M1.z, A1.w * M1.w);
      const float e44 = (q == 1) ? 1.0f : B1.x * N1.x;  // bias row k=108
      po3[nt] = pack8(B0.x * N0.x, B0.y * N0.y, B0.z * N0.z, B0.w * N0.w,
                      e44, B1.y * N1.y, B1.z * N1.z, B1.w * N1.w);
    }
  };

  f32x4 hc[NT][4] = {};
  issue_obs(T_ - 1);
  pack_obs();

#pragma unroll 1
  for (int s = 0; s < T_; ++s) {
    const int t = T_ - 1 - s;
    if (t > 0) issue_obs(t - 1);  // land during this step's compute

    bf16x8 bh[NT][2];
    repack2(hc, bh);
#pragma unroll
    for (int nt = 0; nt < NT; ++nt)
#pragma unroll
      for (int tau = 0; tau < 4; ++tau) {
        f32x4 acc = {0.f, 0.f, 0.f, 0.f};
        acc = mfma16(Ai[tau][0], bh[nt][0], acc);
        acc = mfma16(Ai[tau][1], bh[nt][1], acc);
        acc = mfma16(Ai[tau][2], po2[nt], acc);
        acc = mfma16(Ai[tau][3], po3[nt], acc);
#pragma unroll
        for (int r = 0; r < 4; ++r) hc[nt][tau][r] = tanh_f(acc[r]);
      }
    if (t > 0) pack_obs();  // raw loads have landed by now
  }

  // ================= Phase 2: head, z0, KL =================
  bf16x8 bhF[NT][2];
  repack2(hc, bhF);
  float klt = 0.0f;
  f32x4 z[NT];
#pragma unroll
  for (int nt = 0; nt < NT; ++nt) {
    f32x4 o = mfma16(Ah2o[1], bhF[nt][1], mfma16(Ah2o[0], bhF[nt][0], bo));
    float lv[4];
#pragma unroll
    for (int r = 0; r < 4; ++r)
      lv[r] = __int_as_float(__shfl(__float_as_int(o[r]), lane + 32, 64));
    f32x4 zz = {0.f, 0.f, 0.f, 0.f};
    z[nt] = zz;
    if (q < 2) {
      const float4 ev = *(const float4*)(eps + (size_t)(r0 + 16 * nt + c) * 8 + 4 * q);
#pragma unroll
      for (int r = 0; r < 4; ++r) {
        const float m = o[r];
        z[nt][r] = f4get(ev, r) * fexp(0.5f * lv[r]) + m;
        klt += -0.5f * lv[r] + (fexp(lv[r]) + m * m) * 0.5f - 0.5f;
      }
    }
  }

  __builtin_amdgcn_sched_barrier(0);  // keep phase-3 weight loads below

  // ================= Phase 3: RK4 + fused decoder + NLL =================
  bf16x8 A1[4], A2[4][2], A3[2], Ad1[4], Ad2[3][2];
#pragma unroll
  for (int tau = 0; tau < 4; ++tau) {
    bf16x8 f1, fd;
#pragma unroll
    for (int i = 0; i < 8; ++i) {
      const int k = 8 * q + i;
      f1[i] = (__bf16)(k < 8 ? Wf1[k * 64 + 16 * tau + c] : (k == 8 ? bf1[16 * tau + c] : 0.0f));
      fd[i] = (__bf16)(k < 8 ? Wd1[k * 64 + 16 * tau + c] : (k == 8 ? bd1[16 * tau + c] : 0.0f));
    }
    A1[tau] = f1; Ad1[tau] = fd;
#pragma unroll
    for (int ks = 0; ks < 2; ++ks) {
      bf16x8 g;
#pragma unroll
      for (int i = 0; i < 8; ++i) g[i] = (__bf16)Wf2[(32 * ks + 8 * q + i) * 64 + 16 * tau + c];
      A2[tau][ks] = g;
    }
  }
#pragma unroll
  for (int ks = 0; ks < 2; ++ks) {
    bf16x8 f;
#pragma unroll
    for (int i = 0; i < 8; ++i)
      f[i] = (__bf16)((c < 8) ? Wf3[(32 * ks + 8 * q + i) * 8 + c] : 0.0f);
    A3[ks] = f;
  }
#pragma unroll
  for (int tau = 0; tau < 3; ++tau)
#pragma unroll
    for (int ks = 0; ks < 2; ++ks) {
      bf16x8 f;
      const int m = 16 * tau + c;
#pragma unroll
      for (int i = 0; i < 8; ++i)
        f[i] = (__bf16)((m < 44) ? Wd2[(32 * ks + 8 * q + i) * 44 + m] : 0.0f);
      Ad2[tau][ks] = f;
    }
  f32x4 b2_[4], b3_, bd2_[3];
#pragma unroll
  for (int tau = 0; tau < 4; ++tau)
#pragma unroll
    for (int r = 0; r < 4; ++r) b2_[tau][r] = bf2[16 * tau + 4 * q + r];
#pragma unroll
  for (int r = 0; r < 4; ++r) b3_[r] = (q < 2) ? bf3[4 * q + r] : 0.0f;
#pragma unroll
  for (int tau = 0; tau < 3; ++tau)
#pragma unroll
    for (int r = 0; r < 4; ++r) {
      const int d = 16 * tau + 4 * q + r;
      bd2_[tau][r] = (d < 44) ? bd2[d] : 0.0f;
    }

  // Both-tile feval: 8 -> elu 64 -> elu 64 -> 8 (bias of L1 in k=8 row).
  auto feval2 = [&](const bf16x8* bz, f32x4* kout) {
    f32x4 h[NT][4];
#pragma unroll
    for (int nt = 0; nt < NT; ++nt)
#pragma unroll
      for (int tau = 0; tau < 4; ++tau) {
        f32x4 zero = {0.f, 0.f, 0.f, 0.f};
        h[nt][tau] = mfma16(A1[tau], bz[nt], zero);
#pragma unroll
        for (int r = 0; r < 4; ++r) h[nt][tau][r] = elu_f(h[nt][tau][r]);
      }
    bf16x8 bh[NT][2];
    repack2(h, bh);
    f32x4 g[NT][4];
#pragma unroll
    for (int nt = 0; nt < NT; ++nt)
#pragma unroll
      for (int tau = 0; tau < 4; ++tau) {
        g[nt][tau] = mfma16(A2[tau][1], bh[nt][1], mfma16(A2[tau][0], bh[nt][0], b2_[tau]));
#pragma unroll
        for (int r = 0; r < 4; ++r) g[nt][tau][r] = elu_f(g[nt][tau][r]);
      }
    bf16x8 bg[NT][2];
    repack2(g, bg);
#pragma unroll
    for (int nt = 0; nt < NT; ++nt)
      kout[nt] = mfma16(A3[1], bg[nt][1], mfma16(A3[0], bg[nt][0], b3_));
  };

  const float dt = 1.0f / (float)(T_ - 1);
  const float hdt = 0.5f * dt;
  float qacc = 0.0f;

#pragma unroll 1
  for (int t = 0; t < T_; ++t) {
    // Issue this step's x/mask loads now; decoder consumes them ~4 fevals later.
    float4 xc[NT][3], mc[NT][3];
#pragma unroll
    for (int nt = 0; nt < NT; ++nt)
#pragma unroll
      for (int tau = 0; tau < 3; ++tau) {
        const int d0 = 16 * tau + 4 * q;
        if (d0 < 44) {
          const size_t off = (size_t)(r0 + 16 * nt + c) * T_ * D_ + (size_t)t * D_ + d0;
          xc[nt][tau] = *(const float4*)(x + off);
          mc[nt][tau] = *(const float4*)(mask + off);
        }
      }

    bf16x8 bzd[NT];
#pragma unroll
    for (int nt = 0; nt < NT; ++nt) bzd[nt] = build_bz(z[nt], c, q);

    // ---- RK4 advance (both tiles interleaved) ----
    if (t < T_ - 1) {
      f32x4 kacc[NT], kc[NT], zt[NT];
      bf16x8 bzt[NT];
      feval2(bzd, kc);
#pragma unroll
      for (int nt = 0; nt < NT; ++nt) {
        kacc[nt] = kc[nt];
#pragma unroll
        for (int r = 0; r < 4; ++r) zt[nt][r] = z[nt][r] + hdt * kc[nt][r];
        bzt[nt] = build_bz(zt[nt], c, q);
      }
      feval2(bzt, kc);
#pragma unroll
      for (int nt = 0; nt < NT; ++nt) {
#pragma unroll
        for (int r = 0; r < 4; ++r) {
          kacc[nt][r] += 2.0f * kc[nt][r];
          zt[nt][r] = z[nt][r] + hdt * kc[nt][r];
        }
        bzt[nt] = build_bz(zt[nt], c, q);
      }
      feval2(bzt, kc);
#pragma unroll
      for (int nt = 0; nt < NT; ++nt) {
#pragma unroll
        for (int r = 0; r < 4; ++r) {
          kacc[nt][r] += 2.0f * kc[nt][r];
          zt[nt][r] = z[nt][r] + dt * kc[nt][r];
        }
        bzt[nt] = build_bz(zt[nt], c, q);
      }
      feval2(bzt, kc);
#pragma unroll
      for (int nt = 0; nt < NT; ++nt)
#pragma unroll
        for (int r = 0; r < 4; ++r)
          z[nt][r] += (dt / 6.0f) * (kacc[nt][r] + kc[nt][r]);
    }

    // ---- decoder on z_t + masked NLL (x loads long landed) ----
    f32x4 hd[NT][4];
#pragma unroll
    for (int nt = 0; nt < NT; ++nt)
#pragma unroll
      for (int tau = 0; tau < 4; ++tau) {
        f32x4 zero = {0.f, 0.f, 0.f, 0.f};
        hd[nt][tau] = mfma16(Ad1[tau], bzd[nt], zero);
#pragma unroll
        for (int r = 0; r < 4; ++r) hd[nt][tau][r] = fmaxf(hd[nt][tau][r], 0.0f);
      }
    bf16x8 bhd[NT][2];
    repack2(hd, bhd);
#pragma unroll
    for (int nt = 0; nt < NT; ++nt)
#pragma unroll
      for (int tau = 0; tau < 3; ++tau) {
        f32x4 p = mfma16(Ad2[tau][1], bhd[nt][1], mfma16(Ad2[tau][0], bhd[nt][0], bd2_[tau]));
        if (16 * tau + 4 * q < 44) {
#pragma unroll
          for (int r = 0; r < 4; ++r) {
            const float xa = f4get(xc[nt][tau], r), ma = f4get(mc[nt][tau], r);
            const float mx = xa * ma;
            const float upd = (mx != 0.0f) ? mx : p[r];
            const float df = xa - upd;
            qacc += df * df;
          }
        }
      }
  }

  // ---- per-wave partial: scaled SSE + per-lane KL, one butterfly ----
  float tot = qacc * (0.5f / 0.09f) + klt;
  tot += __shfl_xor(tot, 1);  tot += __shfl_xor(tot, 2);
  tot += __shfl_xor(tot, 4);  tot += __shfl_xor(tot, 8);
  tot += __shfl_xor(tot, 16); tot += __shfl_xor(tot, 32);
  if (lane == 0) part[blockIdx.x] = tot;
}

// =================== final reduction: 256 partials -> loss ===================
__global__ __launch_bounds__(256) void reduce_kernel(const float* __restrict__ part,
                                                     float* __restrict__ out) {
  __shared__ float s[4];
  const int tid = threadIdx.x;
  float v = part[tid];
  v += __shfl_xor(v, 1);  v += __shfl_xor(v, 2);
  v += __shfl_xor(v, 4);  v += __shfl_xor(v, 8);
  v += __shfl_xor(v, 16); v += __shfl_xor(v, 32);
  if ((tid & 63) == 0) s[tid >> 6] = v;
  __syncthreads();
  if (tid == 0) {
    float acc = s[0] + s[1] + s[2] + s[3];
    const float c0 = 0.28503427112126353f;  // -0.5*(log(2pi)+2*log(0.3))
    out[0] = acc * (1.0f / (float)B_) - (float)(T_ * D_) * c0;
  }
}

extern "C" void kernel_launch(void* const* d_in, const int* in_sizes, int n_in,
                              void* d_out, int out_size, void* d_ws, size_t ws_size,
                              hipStream_t stream) {
  const float* x    = (const float*)d_in[0];
  const float* mask = (const float*)d_in[1];
  const float* eps  = (const float*)d_in[2];
  const float* Wi2h = (const float*)d_in[3];
  const float* bi2h = (const float*)d_in[4];
  const float* Wh2o = (const float*)d_in[5];
  const float* bh2o = (const float*)d_in[6];
  const float* Wf1  = (const float*)d_in[7];
  const float* bf1  = (const float*)d_in[8];
  const float* Wf2  = (const float*)d_in[9];
  const float* bf2  = (const float*)d_in[10];
  const float* Wf3  = (const float*)d_in[11];
  const float* bf3  = (const float*)d_in[12];
  const float* Wd1  = (const float*)d_in[13];
  const float* bd1  = (const float*)d_in[14];
  const float* Wd2  = (const float*)d_in[15];
  const float* bd2  = (const float*)d_in[16];

  float* loss = (float*)d_out;
  float* part = (float*)d_ws;  // 256 floats

  fused_kernel<<<dim3(B_ / (16 * NT)), dim3(64), 0, stream>>>(
      x, mask, eps, Wi2h, bi2h, Wh2o, bh2o, Wf1, bf1, Wf2, bf2, Wf3, bf3,
      Wd1, bd1, Wd2, bd2, part);
  reduce_kernel<<<dim3(1), dim3(256), 0, stream>>>(part, loss);
}